// Round 11
// baseline (1365.871 us; speedup 1.0000x reference)
//
#include <hip/hip_runtime.h>
#include <stdint.h>

#define T_DIM 512
#define B_DIM 256
#define OBS_DIM 128
#define H_DIM 256
#define A_DIM 32
#define TB (T_DIM*B_DIM)   // 131072

typedef unsigned short u16;
typedef unsigned int   u32;
typedef _Float16 half2v __attribute__((ext_vector_type(2)));
typedef __attribute__((ext_vector_type(8))) short short8;   // 8 bf16 (4 VGPRs)
typedef __attribute__((ext_vector_type(4))) float f32x4;
typedef __attribute__((ext_vector_type(4))) u32   u32x4;

__device__ __forceinline__ float bf2f(u16 v){ return __uint_as_float(((u32)v)<<16); }
__device__ __forceinline__ u16 f2bf(float f){
    u32 x = __float_as_uint(f);
    u32 r = x + 0x7fffu + ((x>>16)&1u);   // round-to-nearest-even
    return (u16)(r>>16);
}
__device__ __forceinline__ float2 bfpair(u32 u){
    return make_float2(__uint_as_float(u<<16), __uint_as_float(u & 0xffff0000u));
}

// packed-f16-pair dot: acc += a.lo*b.lo + a.hi*b.hi
__device__ __forceinline__ float dot2(u32 a, u32 b, float c){
#if __has_builtin(__builtin_amdgcn_fdot2)
    return __builtin_amdgcn_fdot2(__builtin_bit_cast(half2v,a),
                                  __builtin_bit_cast(half2v,b), c, false);
#else
    half2v ha = __builtin_bit_cast(half2v,a), hb = __builtin_bit_cast(half2v,b);
    return fmaf((float)ha[0],(float)hb[0], fmaf((float)ha[1],(float)hb[1], c));
#endif
}

// inline-asm dot2 (R7): measured identical to the intrinsic (the allocator's
// AGPR parking + per-use copy is unavoidable either way); kept as-is.
#define DOT2A(acc, w, h) \
    asm("v_dot2_f32_f16 %0, %1, %2, %0" : "+v"(acc) : "v"(w), "v"(h))

// async global->LDS 16B copy: LDS dest is wave-uniform base + lane*16,
// global src is per-lane (m97 ladder step; R9: +38us on these GEMMs).
#define GLOAD16(gsrc, ldst) \
    __builtin_amdgcn_global_load_lds( \
        (const __attribute__((address_space(1))) void*)(gsrc), \
        (__attribute__((address_space(3))) void*)(ldst), 16, 0, 0)

// LDS-only barrier: drain lgkmcnt, leave vmcnt floating (y stores / gi loads
// are only consumed by their issuing thread -- compiler tracks those waits).
// __syncthreads would drain vmcnt(0) too, exposing the y-store retire latency
// to all 16 waves every step (m201/m139 pattern: raw s_barrier is safe).
#define LDS_BARRIER() do { \
    asm volatile("s_waitcnt lgkmcnt(0)" ::: "memory"); \
    __builtin_amdgcn_s_barrier(); \
} while(0)

// ---------------------------------------------------------------------------
// dones dtype probe (u8 bool vs i32 vs f32) via nonzero byte positions mod 4.
// ---------------------------------------------------------------------------
__global__ void zero_flags_kernel(int* p){ if(threadIdx.x<4) p[threadIdx.x]=0; }

__global__ void detect_kernel(const unsigned char* __restrict__ d, int n, int* __restrict__ flags){
    int f=0;
    for(int p = blockIdx.x*blockDim.x+threadIdx.x; p<n; p += gridDim.x*blockDim.x){
        if(d[p]){ int m=p&3; if(m==1) f|=1; else if(m>=2) f|=2; }
    }
    if(f) atomicOr(flags, f);
}

// concat b_a1(256) | b_c1(256) -> b_ac(512) for the fused head-1 GEMM
__global__ void concat_bias_kernel(const float* __restrict__ a, const float* __restrict__ b,
                                   float* __restrict__ dst){
    int i = threadIdx.x;
    dst[i] = a[i];
    dst[256 + i] = b[i];
}

// ---------------------------------------------------------------------------
// Recurrent weights -> packed f16 pairs: dst[((m*32+q)*256 + j)*4 + e] packs
// k=2*(4q+e), 2*(4q+e)+1 of column j of matrix m (q covers k=8q..8q+7).
// ---------------------------------------------------------------------------
__global__ void cvt_wt_kernel(const float* __restrict__ Whr, const float* __restrict__ Whz,
                              const float* __restrict__ Whn, u32* __restrict__ dst){
    int i = blockIdx.x*blockDim.x + threadIdx.x;
    if(i >= 3*32*256*4) return;
    int e = i & 3;
    int j = (i >> 2) & 255;
    int q = (i >> 10) & 31;
    int m = i >> 15;
    const float* W = (m==0) ? Whr : (m==1) ? Whz : Whn;
    int kp = q*4 + e, k = 2*kp;
    _Float16 lo = (_Float16)W[(size_t)k    *H_DIM + j];
    _Float16 hi = (_Float16)W[(size_t)(k+1)*H_DIM + j];
    dst[i] = (u32)__builtin_bit_cast(u16,lo) | ((u32)__builtin_bit_cast(u16,hi) << 16);
}

// GEMM weight f32 [K][N] -> bf16 transposed [N][K]
__global__ void cvt_wT_kernel(const float* __restrict__ W, u16* __restrict__ dst,
                              int K, int N){
    int i = blockIdx.x*blockDim.x + threadIdx.x;
    if(i >= K*N) return;
    int n = i / K;
    int k = i - n*K;
    dst[i] = f2bf(W[(size_t)k*N + n]);
}

// ---------------------------------------------------------------------------
// MFMA bf16 GEMM: C[M,N](bf16) = opt_relu(A @ Bt^T + bias), Bt bf16 [N][K].
// A is bf16 (AF32=0) or f32 converted during staging (AF32=1).
// 128x128 tile, BK=32, 4 waves 2x2, 16x mfma_f32_16x16x32_bf16 each.
// bf16 staging via global_load_lds width=16 (R9).
// ---------------------------------------------------------------------------
template<int RELU, int AF32>
__global__ __launch_bounds__(256, 2)
void gemm_mfma_kernel(const void* __restrict__ A_, const u16* __restrict__ Bt,
                      const float* __restrict__ bias, u16* __restrict__ C,
                      int M, int N, int K)
{
    __shared__ u16 As[128*32];
    __shared__ u16 Bs[128*32];
    const int tid  = threadIdx.x;
    const int wave = tid >> 6;
    const int lane = tid & 63;
    const int ln15 = lane & 15;
    const int quad = lane >> 4;
    const int wm = wave & 1, wn = wave >> 1;
    const int rowBase = blockIdx.y*128;
    const int colBase = blockIdx.x*128;

    f32x4 acc[4][4] = {};

    // async-staging decomposition (bf16 tiles)
    const int rA   = tid >> 2;          // row within 64-row chunk
    const int cA   = (tid & 3) * 8;     // col offset in u16
    u16* AsW0 = As + wave*512;          // chunk0 LDS base (bytes wave*1024)
    u16* AsW1 = As + 2048 + wave*512;   // chunk1 (+4096 B)
    u16* BsW0 = Bs + wave*512;
    u16* BsW1 = Bs + 2048 + wave*512;

    // AF32 fallback staging coords
    const int sr = tid >> 1;
    const int sc = (tid & 1) * 16;

    for(int kb = 0; kb < K; kb += 32){
        if(AF32){
            const float* af = (const float*)A_;
            const float* ag = af + (size_t)(rowBase+sr)*K + kb + sc;
            float4 f0 = *(const float4*)ag;
            float4 f1 = *(const float4*)(ag+4);
            float4 f2 = *(const float4*)(ag+8);
            float4 f3 = *(const float4*)(ag+12);
            u16 tmp[16] = { f2bf(f0.x),f2bf(f0.y),f2bf(f0.z),f2bf(f0.w),
                            f2bf(f1.x),f2bf(f1.y),f2bf(f1.z),f2bf(f1.w),
                            f2bf(f2.x),f2bf(f2.y),f2bf(f2.z),f2bf(f2.w),
                            f2bf(f3.x),f2bf(f3.y),f2bf(f3.z),f2bf(f3.w) };
            *(uint4*)&As[sr*32 + sc]     = *(const uint4*)&tmp[0];
            *(uint4*)&As[sr*32 + sc + 8] = *(const uint4*)&tmp[8];
        } else {
            const u16* ab = (const u16*)A_;
            GLOAD16(ab + (size_t)(rowBase +      rA)*K + kb + cA, AsW0);
            GLOAD16(ab + (size_t)(rowBase + 64 + rA)*K + kb + cA, AsW1);
        }
        GLOAD16(Bt + (size_t)(colBase +      rA)*K + kb + cA, BsW0);
        GLOAD16(Bt + (size_t)(colBase + 64 + rA)*K + kb + cA, BsW1);
        __syncthreads();

        short8 af[4], bf[4];
        #pragma unroll
        for(int mt=0;mt<4;mt++)
            af[mt] = *(const short8*)&As[(wm*64+mt*16+ln15)*32 + quad*8];
        #pragma unroll
        for(int nt=0;nt<4;nt++)
            bf[nt] = *(const short8*)&Bs[(wn*64+nt*16+ln15)*32 + quad*8];
        #pragma unroll
        for(int mt=0;mt<4;mt++){
            #pragma unroll
            for(int nt=0;nt<4;nt++){
                acc[mt][nt] = __builtin_amdgcn_mfma_f32_16x16x32_bf16(
                                  af[mt], bf[nt], acc[mt][nt], 0, 0, 0);
            }
        }
        __syncthreads();
    }

    #pragma unroll
    for(int nt=0;nt<4;nt++){
        int n = colBase + wn*64 + nt*16 + ln15;
        float bv = bias[n];
        #pragma unroll
        for(int mt=0;mt<4;mt++){
            #pragma unroll
            for(int r=0;r<4;r++){
                int m = rowBase + wm*64 + mt*16 + quad*4 + r;
                float v = acc[mt][nt][r] + bv;
                if(RELU) v = fmaxf(v, 0.f);
                C[(size_t)m*N + n] = f2bf(v);
            }
        }
    }
}

// ---------------------------------------------------------------------------
// GRU scan (R2/R7 dot structure -- settled). 256 blocks x 1024 threads;
// thread (g=k-quarter, j=column) owns k-range [64g,64g+64) of column j for
// all 3 matrices (96 packed-f16 u32; allocator AGPR-parks them, tax accepted
// -- R2/R3/R5/R7).
// R11 (corrected model: scan cost is ~1.45us/step FLAT, 743us total = 66% of
// runtime; "fixed dispatch cost" was a misread -- R8/R9 ran Tc=256 all along):
//  (a) both per-step __syncthreads -> LDS_BARRIER (lgkmcnt-only drain + raw
//      s_barrier). __syncthreads drains vmcnt(0) too, exposing the y-store
//      retire + gi-load latency to all 16 waves every step (~200-400cyc).
//      Cross-wave deps here are LDS-only (rex, hbuf) -> lgkm drain suffices.
//  (b) partial exchange packed as float4: 1 ds_write_b128 / 3 ds_read_b128
//      instead of 3/9 scalar ops -> shorter gate-phase LDS chain.
// ---------------------------------------------------------------------------
__global__ __attribute__((amdgpu_flat_work_group_size(1024,1024), amdgpu_waves_per_eu(4,4)))
void scan_kernel(const u16* __restrict__ gi, const void* __restrict__ dones,
                 const int* __restrict__ flags, const u32x4* __restrict__ Wt4,
                 const float* __restrict__ bhn, float* __restrict__ h_carry,
                 u16* __restrict__ y, int t0, int Tc)
{
    __shared__ __align__(16) u32 hbuf[2][128];   // 256 packed f16 each
    __shared__ float4 rex4[4][256];              // partial dots (g=1..3 used): x=r,y=z,z=n
    const int tid = threadIdx.x;
    const int j   = tid & 255;
    const int g   = tid >> 8;      // k-quarter 0..3
    const int row = blockIdx.x;
    const int fl  = flags[0];
    const int mode = (fl&1) ? 0 : ((fl&2) ? 2 : 1);  // 0=u8, 1=i32, 2=f32

    auto getdone = [&](int t)->bool{
        int idx = t*B_DIM + row;
        if(mode==0) return ((const unsigned char*)dones)[idx] != 0;
        if(mode==1) return ((const int*)dones)[idx] != 0;
        return ((const float*)dones)[idx] != 0.f;
    };

    // ---- one-time weight load: k-quarter g of column j, all three mats ----
    const u32x4* baseR = Wt4 + (size_t)( 0 + g*8)*256 + j;
    const u32x4* baseZ = Wt4 + (size_t)(32 + g*8)*256 + j;
    const u32x4* baseN = Wt4 + (size_t)(64 + g*8)*256 + j;
    u32 wr[32], wz[32], wn[32];
    #pragma unroll
    for(int q=0;q<8;q++){
        u32x4 tr = baseR[(size_t)q*256]; wr[4*q]=tr[0]; wr[4*q+1]=tr[1]; wr[4*q+2]=tr[2]; wr[4*q+3]=tr[3];
        u32x4 tz = baseZ[(size_t)q*256]; wz[4*q]=tz[0]; wz[4*q+1]=tz[1]; wz[4*q+2]=tz[2]; wz[4*q+3]=tz[3];
        u32x4 tn = baseN[(size_t)q*256]; wn[4*q]=tn[0]; wn[4*q+1]=tn[1]; wn[4*q+2]=tn[2]; wn[4*q+3]=tn[3];
    }

    const float bh = bhn[j];
    float hoj = 0.f;
    if(g == 0){
        bool d0 = getdone(t0);
        hoj = d0 ? 0.f : h_carry[(size_t)row*H_DIM + j];
        ((_Float16*)hbuf[0])[j] = (_Float16)hoj;
    }
    __syncthreads();   // prologue: full barrier once (cold path)

    int cur = 0;
    for(int t=0; t<Tc; ++t){
        // gate-input loads up front (latency hides under the dot phase)
        size_t gbase = ((size_t)t*B_DIM + row)*768;
        float ir=0.f, izv=0.f, inn=0.f; bool dn=false;
        if(g == 0){
            ir  = bf2f(gi[gbase + j]);
            izv = bf2f(gi[gbase + 256 + j]);
            inn = bf2f(gi[gbase + 512 + j]);
            dn  = (t < Tc-1) ? getdone(t0+t+1) : false;
        }

        // partial dots over this thread's k-quarter, all three matrices.
        // hv is a wave-uniform broadcast read, reused across r/z/n.
        float r0=0.f,r1=0.f,z0=0.f,z1=0.f,n0=0.f,n1=0.f;
        const u32x4* hb = (const u32x4*)hbuf[cur] + g*8;
        #pragma unroll
        for(int q=0;q<8;q++){
            u32x4 hv = hb[q];
            DOT2A(r0, wr[4*q  ], hv[0]); DOT2A(r1, wr[4*q+1], hv[1]);
            DOT2A(r0, wr[4*q+2], hv[2]); DOT2A(r1, wr[4*q+3], hv[3]);
            DOT2A(z0, wz[4*q  ], hv[0]); DOT2A(z1, wz[4*q+1], hv[1]);
            DOT2A(z0, wz[4*q+2], hv[2]); DOT2A(z1, wz[4*q+3], hv[3]);
            DOT2A(n0, wn[4*q  ], hv[0]); DOT2A(n1, wn[4*q+1], hv[1]);
            DOT2A(n0, wn[4*q+2], hv[2]); DOT2A(n1, wn[4*q+3], hv[3]);
        }
        if(g != 0){
            rex4[g][j] = make_float4(r0 + r1, z0 + z1, n0 + n1, 0.f);
        }
        LDS_BARRIER();   // rex visible; vmcnt (gi loads) left floating

        if(g == 0){
            float4 p1 = rex4[1][j];
            float4 p2 = rex4[2][j];
            float4 p3 = rex4[3][j];
            float rt = (r0 + r1) + p1.x + (p2.x + p3.x);
            float zt = (z0 + z1) + p1.y + (p2.y + p3.y);
            float nt = (n0 + n1) + p1.z + (p2.z + p3.z);
            float r = 1.f/(1.f + __expf(-(ir + rt)));
            float z = 1.f/(1.f + __expf(-(izv + zt)));
            float x = inn + r*(nt + bh);
            float e2 = __expf(2.f*x);
            float n = 1.f - 2.f/(e2 + 1.f);          // tanh(x)
            float hn = (1.f - z)*n + z*hoj;
            hoj = dn ? 0.f : hn;                     // dn=false on last chunk step
            ((_Float16*)hbuf[cur^1])[j] = (_Float16)hoj;   // LDS write first
            y[((size_t)t*B_DIM + row)*H_DIM + j] = f2bf(hn); // store floats (no drain)
        }
        LDS_BARRIER();   // hbuf[cur^1] visible; y store NOT drained
        cur ^= 1;
    }

    if(g == 0) h_carry[(size_t)row*H_DIM + j] = hoj;  // raw carry
}

// ---------------------------------------------------------------------------
// Actor head stage 2: logits[rows,32] = ah[rows,:256 of ld] @ W_a2 + b_a2 - (1-avail)*1e10
// ---------------------------------------------------------------------------
__global__ __launch_bounds__(256)
void actor2_kernel(const u16* __restrict__ ah, int ld, const float* __restrict__ W_a2,
                   const float* __restrict__ b_a2, const float* __restrict__ avail,
                   float* __restrict__ logits)
{
    __shared__ u16 ahs[64][264];
    const int tid = threadIdx.x;
    const int r0 = blockIdx.x*64;
    {
        int row = tid & 63;
        int c0 = (tid >> 6) * 64;
        const uint4* gp = (const uint4*)(ah + (size_t)(r0+row)*ld + c0);
        #pragma unroll
        for(int q=0;q<8;q++){
            uint4 u = gp[q];
            u32* dst = (u32*)&ahs[row][c0 + q*8];
            dst[0]=u.x; dst[1]=u.y; dst[2]=u.z; dst[3]=u.w;
        }
    }
    __syncthreads();
    const int c  = tid & 31;
    const int rg = tid >> 5;   // 0..7
    float acc[8]={0.f,0.f,0.f,0.f,0.f,0.f,0.f,0.f};
    float bc = b_a2[c];
    for(int k=0;k<H_DIM;k+=4){
        float w0 = W_a2[(k+0)*A_DIM + c];
        float w1 = W_a2[(k+1)*A_DIM + c];
        float w2 = W_a2[(k+2)*A_DIM + c];
        float w3 = W_a2[(k+3)*A_DIM + c];
        #pragma unroll
        for(int rr=0;rr<8;rr++){
            uint2 av = *(const uint2*)&ahs[rg*8+rr][k];
            float2 p0 = bfpair(av.x), p1 = bfpair(av.y);
            acc[rr] = fmaf(p0.x,w0,fmaf(p0.y,w1,fmaf(p1.x,w2,fmaf(p1.y,w3,acc[rr]))));
        }
    }
    #pragma unroll
    for(int rr=0;rr<8;rr++){
        int grow = r0 + rg*8 + rr;
        float av = avail[(size_t)grow*A_DIM + c];
        logits[(size_t)grow*A_DIM + c] = acc[rr] + bc - (1.f-av)*1e10f;
    }
}

// ---------------------------------------------------------------------------
// Critic head stage 2: value[row] = ch[row,:256 of ld] @ W_c2 + b_c2. Wave per row.
// ---------------------------------------------------------------------------
__global__ __launch_bounds__(256)
void critic2_kernel(const u16* __restrict__ ch, int ld, const float* __restrict__ W_c2,
                    const float* __restrict__ b_c2, float* __restrict__ value)
{
    const int lane = threadIdx.x & 63;
    const int wid  = threadIdx.x >> 6;
    const int row  = blockIdx.x*4 + wid;
    uint2 av = *(const uint2*)(ch + (size_t)row*ld + lane*4);
    float2 p0 = bfpair(av.x), p1 = bfpair(av.y);
    float4 wv = *(const float4*)(W_c2 + lane*4);
    float acc = p0.x*wv.x + p0.y*wv.y + p1.x*wv.z + p1.y*wv.w;
    #pragma unroll
    for(int off=32; off>0; off>>=1) acc += __shfl_down(acc, off, 64);
    if(lane==0) value[row] = acc + b_c2[0];
}

// ---------------------------------------------------------------------------
extern "C" void kernel_launch(void* const* d_in, const int* in_sizes, int n_in,
                              void* d_out, int out_size, void* d_ws, size_t ws_size,
                              hipStream_t stream)
{
    const float* hidden = (const float*)d_in[0];
    const float* obs    = (const float*)d_in[1];
    const void*  dones  = d_in[2];
    const float* avail  = (const float*)d_in[3];
    const float* W_emb  = (const float*)d_in[4];
    const float* b_emb  = (const float*)d_in[5];
    const float* Wi     = (const float*)d_in[6];
    const float* bi     = (const float*)d_in[7];
    const float* Whr    = (const float*)d_in[8];
    const float* Whz    = (const float*)d_in[9];
    const float* Whn    = (const float*)d_in[10];
    const float* bhn    = (const float*)d_in[11];
    const float* W_a1   = (const float*)d_in[12];
    const float* b_a1   = (const float*)d_in[13];
    const float* W_a2   = (const float*)d_in[14];
    const float* b_a2   = (const float*)d_in[15];
    const float* W_c1   = (const float*)d_in[16];
    const float* b_c1   = (const float*)d_in[17];
    const float* W_c2   = (const float*)d_in[18];
    const float* b_c2   = (const float*)d_in[19];

    float* out_hidden = (float*)d_out;                       // 65536
    float* out_logits = out_hidden + (size_t)B_DIM*H_DIM;    // 4194304
    float* out_value  = out_logits + (size_t)TB*A_DIM;       // 131072

    // ---- workspace layout (chunk size adapted to ws_size, deterministic) ----
    // ws_size is known to lie in [203MB, 403MB) (R8's cand=512 never fit):
    // Tc=256 / NC=2 is the operating point (measured best for non-scan).
    const size_t fixed = 393216 + 393216 + 262144 + 65536 + 262144 + 256 + 2048;
    int Tc = 4;
    for(int cand = 256; cand >= 4; cand >>= 1){
        size_t need = fixed + (size_t)cand*(393216 /*gi*/ + 262144 /*emb|ac*/ + 131072 /*y*/);
        if(need <= ws_size){ Tc = cand; break; }
    }
    const int NC = T_DIM / Tc;

    uint8_t* ws = (uint8_t*)d_ws;
    size_t off = 0;
    u32*  wt_b    = (u32*)(ws + off); off += 393216;   // scan weights, packed f16
    u16*  wiT     = (u16*)(ws + off); off += 393216;   // Wi^T bf16 [768][256]
    u16*  wacT    = (u16*)(ws + off); off += 262144;   // [W_a1^T | W_c1^T] bf16 [512][256]
    u16*  wembT   = (u16*)(ws + off); off += 65536;    // W_emb^T bf16 [256][128]
    float* h_carry= (float*)(ws + off); off += 262144;
    int*  flags   = (int*)(ws + off); off += 256;
    float* b_ac   = (float*)(ws + off); off += 2048;   // b_a1|b_c1 (512 f32)
    u16*  gi_c    = (u16*)(ws + off); off += (size_t)Tc*393216;
    u16*  embac_c = (u16*)(ws + off); off += (size_t)Tc*262144;  // emb [Mc][256], later ac [Mc][512]
    u16*  y_c     = (u16*)(ws + off); off += (size_t)Tc*131072;
    u16*  emb_c   = embac_c;
    u16*  ac_c    = embac_c;

    zero_flags_kernel<<<1, 64, 0, stream>>>(flags);
    detect_kernel<<<64, 256, 0, stream>>>((const unsigned char*)dones, TB, flags);
    cvt_wt_kernel<<<384, 256, 0, stream>>>(Whr, Whz, Whn, wt_b);
    cvt_wT_kernel<<<768, 256, 0, stream>>>(Wi,   wiT,  256, 768);
    cvt_wT_kernel<<<256, 256, 0, stream>>>(W_a1, wacT,          256, 256);
    cvt_wT_kernel<<<256, 256, 0, stream>>>(W_c1, wacT + 65536,  256, 256);
    cvt_wT_kernel<<<128, 256, 0, stream>>>(W_emb, wembT, 128, 256);
    concat_bias_kernel<<<1, 256, 0, stream>>>(b_a1, b_c1, b_ac);
    hipMemcpyAsync(h_carry, hidden, (size_t)B_DIM*H_DIM*sizeof(float),
                   hipMemcpyDeviceToDevice, stream);

    const int Mc = Tc*B_DIM;
    const int gy = Mc/128;

    for(int c = 0; c < NC; ++c){
        const int t0 = c*Tc;
        const float* obs_c = obs + (size_t)t0*B_DIM*OBS_DIM;
        // emb = relu(obs @ W_emb + b_emb)  (MFMA, f32 A converted in staging)
        gemm_mfma_kernel<1,1><<<dim3(2,gy), 256, 0, stream>>>(obs_c, wembT, b_emb, emb_c, Mc, 256, 128);
        // gi = emb @ Wi + bi  (MFMA)
        gemm_mfma_kernel<0,0><<<dim3(6,gy), 256, 0, stream>>>(emb_c, wiT, bi, gi_c, Mc, 768, 256);
        // GRU scan chunk: 256 blocks (one per batch row) x 1024 threads
        scan_kernel<<<256, 1024, 0, stream>>>(gi_c, dones, flags, (const u32x4*)wt_b,
                                              bhn, h_carry, y_c, t0, Tc);
        // fused actor1|critic1 head: [Mc][512] = relu(y @ [W_a1|W_c1] + b_ac)
        gemm_mfma_kernel<1,0><<<dim3(4,gy), 256, 0, stream>>>(y_c, wacT, b_ac, ac_c, Mc, 512, 256);
        actor2_kernel<<<Mc/64, 256, 0, stream>>>(ac_c, 512, W_a2, b_a2,
                                                 avail + (size_t)t0*B_DIM*A_DIM,
                                                 out_logits + (size_t)t0*B_DIM*A_DIM);
        critic2_kernel<<<Mc/4, 256, 0, stream>>>(ac_c + 256, 512, W_c2, b_c2,
                                                 out_value + (size_t)t0*B_DIM);
    }

    hipMemcpyAsync(out_hidden, h_carry, (size_t)B_DIM*H_DIM*sizeof(float),
                   hipMemcpyDeviceToDevice, stream);
}

// Round 13
// 1120.930 us; speedup vs baseline: 1.2185x; 1.2185x over previous
//
#include <hip/hip_runtime.h>
#include <stdint.h>

#define T_DIM 512
#define B_DIM 256
#define OBS_DIM 128
#define H_DIM 256
#define A_DIM 32
#define TB (T_DIM*B_DIM)   // 131072

typedef unsigned short u16;
typedef unsigned int   u32;
typedef _Float16 half2v __attribute__((ext_vector_type(2)));
typedef __attribute__((ext_vector_type(8))) short short8;   // 8 bf16 (4 VGPRs)
typedef __attribute__((ext_vector_type(4))) float f32x4;
typedef __attribute__((ext_vector_type(4))) u32   u32x4;

__device__ __forceinline__ float bf2f(u16 v){ return __uint_as_float(((u32)v)<<16); }
__device__ __forceinline__ u16 f2bf(float f){
    u32 x = __float_as_uint(f);
    u32 r = x + 0x7fffu + ((x>>16)&1u);   // round-to-nearest-even
    return (u16)(r>>16);
}
__device__ __forceinline__ float2 bfpair(u32 u){
    return make_float2(__uint_as_float(u<<16), __uint_as_float(u & 0xffff0000u));
}

// packed-f16-pair dot: acc += a.lo*b.lo + a.hi*b.hi
__device__ __forceinline__ float dot2(u32 a, u32 b, float c){
#if __has_builtin(__builtin_amdgcn_fdot2)
    return __builtin_amdgcn_fdot2(__builtin_bit_cast(half2v,a),
                                  __builtin_bit_cast(half2v,b), c, false);
#else
    half2v ha = __builtin_bit_cast(half2v,a), hb = __builtin_bit_cast(half2v,b);
    return fmaf((float)ha[0],(float)hb[0], fmaf((float)ha[1],(float)hb[1], c));
#endif
}

// inline-asm dot2 (R7): measured identical to the intrinsic (the allocator's
// AGPR parking + per-use copy is unavoidable either way); kept as-is.
#define DOT2A(acc, w, h) \
    asm("v_dot2_f32_f16 %0, %1, %2, %0" : "+v"(acc) : "v"(w), "v"(h))

// async global->LDS 16B copy: LDS dest is wave-uniform base + lane*16,
// global src is per-lane (m97 ladder step; R9: +38us on these GEMMs).
#define GLOAD16(gsrc, ldst) \
    __builtin_amdgcn_global_load_lds( \
        (const __attribute__((address_space(1))) void*)(gsrc), \
        (__attribute__((address_space(3))) void*)(ldst), 16, 0, 0)

// ---------------------------------------------------------------------------
// dones dtype probe (u8 bool vs i32 vs f32) via nonzero byte positions mod 4.
// ---------------------------------------------------------------------------
__global__ void zero_flags_kernel(int* p){ if(threadIdx.x<4) p[threadIdx.x]=0; }

__global__ void detect_kernel(const unsigned char* __restrict__ d, int n, int* __restrict__ flags){
    int f=0;
    for(int p = blockIdx.x*blockDim.x+threadIdx.x; p<n; p += gridDim.x*blockDim.x){
        if(d[p]){ int m=p&3; if(m==1) f|=1; else if(m>=2) f|=2; }
    }
    if(f) atomicOr(flags, f);
}

// concat b_a1(256) | b_c1(256) -> b_ac(512) for the fused head-1 GEMM
__global__ void concat_bias_kernel(const float* __restrict__ a, const float* __restrict__ b,
                                   float* __restrict__ dst){
    int i = threadIdx.x;
    dst[i] = a[i];
    dst[256 + i] = b[i];
}

// ---------------------------------------------------------------------------
// Recurrent weights -> packed f16 pairs: dst[((m*32+q)*256 + j)*4 + e] packs
// k=2*(4q+e), 2*(4q+e)+1 of column j of matrix m (q covers k=8q..8q+7).
// ---------------------------------------------------------------------------
__global__ void cvt_wt_kernel(const float* __restrict__ Whr, const float* __restrict__ Whz,
                              const float* __restrict__ Whn, u32* __restrict__ dst){
    int i = blockIdx.x*blockDim.x + threadIdx.x;
    if(i >= 3*32*256*4) return;
    int e = i & 3;
    int j = (i >> 2) & 255;
    int q = (i >> 10) & 31;
    int m = i >> 15;
    const float* W = (m==0) ? Whr : (m==1) ? Whz : Whn;
    int kp = q*4 + e, k = 2*kp;
    _Float16 lo = (_Float16)W[(size_t)k    *H_DIM + j];
    _Float16 hi = (_Float16)W[(size_t)(k+1)*H_DIM + j];
    dst[i] = (u32)__builtin_bit_cast(u16,lo) | ((u32)__builtin_bit_cast(u16,hi) << 16);
}

// GEMM weight f32 [K][N] -> bf16 transposed [N][K]
__global__ void cvt_wT_kernel(const float* __restrict__ W, u16* __restrict__ dst,
                              int K, int N){
    int i = blockIdx.x*blockDim.x + threadIdx.x;
    if(i >= K*N) return;
    int n = i / K;
    int k = i - n*K;
    dst[i] = f2bf(W[(size_t)k*N + n]);
}

// ---------------------------------------------------------------------------
// MFMA bf16 GEMM: C[M,N](bf16) = opt_relu(A @ Bt^T + bias), Bt bf16 [N][K].
// A is bf16 (AF32=0) or f32 converted during staging (AF32=1).
// 128x128 tile, BK=32, 4 waves 2x2, 16x mfma_f32_16x16x32_bf16 each.
// bf16 staging via global_load_lds width=16 (R9).
// ---------------------------------------------------------------------------
template<int RELU, int AF32>
__global__ __launch_bounds__(256, 2)
void gemm_mfma_kernel(const void* __restrict__ A_, const u16* __restrict__ Bt,
                      const float* __restrict__ bias, u16* __restrict__ C,
                      int M, int N, int K)
{
    __shared__ u16 As[128*32];
    __shared__ u16 Bs[128*32];
    const int tid  = threadIdx.x;
    const int wave = tid >> 6;
    const int lane = tid & 63;
    const int ln15 = lane & 15;
    const int quad = lane >> 4;
    const int wm = wave & 1, wn = wave >> 1;
    const int rowBase = blockIdx.y*128;
    const int colBase = blockIdx.x*128;

    f32x4 acc[4][4] = {};

    // async-staging decomposition (bf16 tiles)
    const int rA   = tid >> 2;          // row within 64-row chunk
    const int cA   = (tid & 3) * 8;     // col offset in u16
    u16* AsW0 = As + wave*512;          // chunk0 LDS base (bytes wave*1024)
    u16* AsW1 = As + 2048 + wave*512;   // chunk1 (+4096 B)
    u16* BsW0 = Bs + wave*512;
    u16* BsW1 = Bs + 2048 + wave*512;

    // AF32 fallback staging coords
    const int sr = tid >> 1;
    const int sc = (tid & 1) * 16;

    for(int kb = 0; kb < K; kb += 32){
        if(AF32){
            const float* af = (const float*)A_;
            const float* ag = af + (size_t)(rowBase+sr)*K + kb + sc;
            float4 f0 = *(const float4*)ag;
            float4 f1 = *(const float4*)(ag+4);
            float4 f2 = *(const float4*)(ag+8);
            float4 f3 = *(const float4*)(ag+12);
            u16 tmp[16] = { f2bf(f0.x),f2bf(f0.y),f2bf(f0.z),f2bf(f0.w),
                            f2bf(f1.x),f2bf(f1.y),f2bf(f1.z),f2bf(f1.w),
                            f2bf(f2.x),f2bf(f2.y),f2bf(f2.z),f2bf(f2.w),
                            f2bf(f3.x),f2bf(f3.y),f2bf(f3.z),f2bf(f3.w) };
            *(uint4*)&As[sr*32 + sc]     = *(const uint4*)&tmp[0];
            *(uint4*)&As[sr*32 + sc + 8] = *(const uint4*)&tmp[8];
        } else {
            const u16* ab = (const u16*)A_;
            GLOAD16(ab + (size_t)(rowBase +      rA)*K + kb + cA, AsW0);
            GLOAD16(ab + (size_t)(rowBase + 64 + rA)*K + kb + cA, AsW1);
        }
        GLOAD16(Bt + (size_t)(colBase +      rA)*K + kb + cA, BsW0);
        GLOAD16(Bt + (size_t)(colBase + 64 + rA)*K + kb + cA, BsW1);
        __syncthreads();

        short8 af[4], bf[4];
        #pragma unroll
        for(int mt=0;mt<4;mt++)
            af[mt] = *(const short8*)&As[(wm*64+mt*16+ln15)*32 + quad*8];
        #pragma unroll
        for(int nt=0;nt<4;nt++)
            bf[nt] = *(const short8*)&Bs[(wn*64+nt*16+ln15)*32 + quad*8];
        #pragma unroll
        for(int mt=0;mt<4;mt++){
            #pragma unroll
            for(int nt=0;nt<4;nt++){
                acc[mt][nt] = __builtin_amdgcn_mfma_f32_16x16x32_bf16(
                                  af[mt], bf[nt], acc[mt][nt], 0, 0, 0);
            }
        }
        __syncthreads();
    }

    #pragma unroll
    for(int nt=0;nt<4;nt++){
        int n = colBase + wn*64 + nt*16 + ln15;
        float bv = bias[n];
        #pragma unroll
        for(int mt=0;mt<4;mt++){
            #pragma unroll
            for(int r=0;r<4;r++){
                int m = rowBase + wm*64 + mt*16 + quad*4 + r;
                float v = acc[mt][nt][r] + bv;
                if(RELU) v = fmaxf(v, 0.f);
                C[(size_t)m*N + n] = f2bf(v);
            }
        }
    }
}

// ---------------------------------------------------------------------------
// GRU scan -- R9/R10-EXACT structure (best measured: 371us/dispatch, Tc=256).
// R11's LDS-only barrier regressed 371->487 (asm "memory" clobber defeated
// compiler scheduling); __syncthreads stays. 256 blocks x 1024 threads;
// thread (g=k-quarter, j=column) owns k-range [64g,64g+64) of column j for
// all 3 matrices (96 packed-f16 u32; allocator AGPR-parks them, tax accepted
// -- R2/R3/R5/R7).
// ---------------------------------------------------------------------------
__global__ __attribute__((amdgpu_flat_work_group_size(1024,1024), amdgpu_waves_per_eu(4,4)))
void scan_kernel(const u16* __restrict__ gi, const void* __restrict__ dones,
                 const int* __restrict__ flags, const u32x4* __restrict__ Wt4,
                 const float* __restrict__ bhn, float* __restrict__ h_carry,
                 u16* __restrict__ y, int t0, int Tc)
{
    __shared__ __align__(16) u32 hbuf[2][128];   // 256 packed f16 each
    __shared__ float rex[3][4][256];             // partial dots (g=1..3 used)
    const int tid = threadIdx.x;
    const int j   = tid & 255;
    const int g   = tid >> 8;      // k-quarter 0..3
    const int row = blockIdx.x;
    const int fl  = flags[0];
    const int mode = (fl&1) ? 0 : ((fl&2) ? 2 : 1);  // 0=u8, 1=i32, 2=f32

    auto getdone = [&](int t)->bool{
        int idx = t*B_DIM + row;
        if(mode==0) return ((const unsigned char*)dones)[idx] != 0;
        if(mode==1) return ((const int*)dones)[idx] != 0;
        return ((const float*)dones)[idx] != 0.f;
    };

    // ---- one-time weight load: k-quarter g of column j, all three mats ----
    const u32x4* baseR = Wt4 + (size_t)( 0 + g*8)*256 + j;
    const u32x4* baseZ = Wt4 + (size_t)(32 + g*8)*256 + j;
    const u32x4* baseN = Wt4 + (size_t)(64 + g*8)*256 + j;
    u32 wr[32], wz[32], wn[32];
    #pragma unroll
    for(int q=0;q<8;q++){
        u32x4 tr = baseR[(size_t)q*256]; wr[4*q]=tr[0]; wr[4*q+1]=tr[1]; wr[4*q+2]=tr[2]; wr[4*q+3]=tr[3];
        u32x4 tz = baseZ[(size_t)q*256]; wz[4*q]=tz[0]; wz[4*q+1]=tz[1]; wz[4*q+2]=tz[2]; wz[4*q+3]=tz[3];
        u32x4 tn = baseN[(size_t)q*256]; wn[4*q]=tn[0]; wn[4*q+1]=tn[1]; wn[4*q+2]=tn[2]; wn[4*q+3]=tn[3];
    }

    const float bh = bhn[j];
    float hoj = 0.f;
    if(g == 0){
        bool d0 = getdone(t0);
        hoj = d0 ? 0.f : h_carry[(size_t)row*H_DIM + j];
        ((_Float16*)hbuf[0])[j] = (_Float16)hoj;
    }
    __syncthreads();

    int cur = 0;
    for(int t=0; t<Tc; ++t){
        // gate-input loads up front (latency hides under the dot phase)
        size_t gbase = ((size_t)t*B_DIM + row)*768;
        float ir=0.f, izv=0.f, inn=0.f; bool dn=false;
        if(g == 0){
            ir  = bf2f(gi[gbase + j]);
            izv = bf2f(gi[gbase + 256 + j]);
            inn = bf2f(gi[gbase + 512 + j]);
            dn  = (t < Tc-1) ? getdone(t0+t+1) : false;
        }

        // partial dots over this thread's k-quarter, all three matrices.
        // hv is a wave-uniform broadcast read, reused across r/z/n.
        float r0=0.f,r1=0.f,z0=0.f,z1=0.f,n0=0.f,n1=0.f;
        const u32x4* hb = (const u32x4*)hbuf[cur] + g*8;
        #pragma unroll
        for(int q=0;q<8;q++){
            u32x4 hv = hb[q];
            DOT2A(r0, wr[4*q  ], hv[0]); DOT2A(r1, wr[4*q+1], hv[1]);
            DOT2A(r0, wr[4*q+2], hv[2]); DOT2A(r1, wr[4*q+3], hv[3]);
            DOT2A(z0, wz[4*q  ], hv[0]); DOT2A(z1, wz[4*q+1], hv[1]);
            DOT2A(z0, wz[4*q+2], hv[2]); DOT2A(z1, wz[4*q+3], hv[3]);
            DOT2A(n0, wn[4*q  ], hv[0]); DOT2A(n1, wn[4*q+1], hv[1]);
            DOT2A(n0, wn[4*q+2], hv[2]); DOT2A(n1, wn[4*q+3], hv[3]);
        }
        if(g != 0){
            rex[0][g][j] = r0 + r1;
            rex[1][g][j] = z0 + z1;
            rex[2][g][j] = n0 + n1;
        }
        __syncthreads();

        if(g == 0){
            float rt = (r0 + r1) + rex[0][1][j] + (rex[0][2][j] + rex[0][3][j]);
            float zt = (z0 + z1) + rex[1][1][j] + (rex[1][2][j] + rex[1][3][j]);
            float nt = (n0 + n1) + rex[2][1][j] + (rex[2][2][j] + rex[2][3][j]);
            float r = 1.f/(1.f + __expf(-(ir + rt)));
            float z = 1.f/(1.f + __expf(-(izv + zt)));
            float x = inn + r*(nt + bh);
            float e2 = __expf(2.f*x);
            float n = 1.f - 2.f/(e2 + 1.f);          // tanh(x)
            float hn = (1.f - z)*n + z*hoj;
            hoj = dn ? 0.f : hn;                     // dn=false on last chunk step
            ((_Float16*)hbuf[cur^1])[j] = (_Float16)hoj;   // issue before y store
            y[((size_t)t*B_DIM + row)*H_DIM + j] = f2bf(hn);
        }
        __syncthreads();
        cur ^= 1;
    }

    if(g == 0) h_carry[(size_t)row*H_DIM + j] = hoj;  // raw carry
}

// ---------------------------------------------------------------------------
// Fused head stage 2 (R12): per 64-row block --
//   actor: logits[rows,32] = ah[rows,:256] @ W_a2 + b_a2 - (1-avail)*1e10
//   critic: value[row] = ch[rows,256:512] @ W_c2 + b_c2 (wave handles 16 rows,
//           loads prefetched 16-deep before the reduce loop).
// Removes the separate 16384-block critic2 dispatch per chunk.
// ---------------------------------------------------------------------------
__global__ __launch_bounds__(256)
void heads_kernel(const u16* __restrict__ ac, int ld, const float* __restrict__ W_a2,
                  const float* __restrict__ b_a2, const float* __restrict__ avail,
                  const float* __restrict__ W_c2, const float* __restrict__ b_c2,
                  float* __restrict__ logits, float* __restrict__ value)
{
    __shared__ u16 ahs[64][264];
    const int tid = threadIdx.x;
    const int r0 = blockIdx.x*64;
    {
        int row = tid & 63;
        int c0 = (tid >> 6) * 64;
        const uint4* gp = (const uint4*)(ac + (size_t)(r0+row)*ld + c0);
        #pragma unroll
        for(int q=0;q<8;q++){
            uint4 u = gp[q];
            u32* dst = (u32*)&ahs[row][c0 + q*8];
            dst[0]=u.x; dst[1]=u.y; dst[2]=u.z; dst[3]=u.w;
        }
    }
    __syncthreads();
    const int c  = tid & 31;
    const int rg = tid >> 5;   // 0..7
    float acc[8]={0.f,0.f,0.f,0.f,0.f,0.f,0.f,0.f};
    float bc = b_a2[c];
    for(int k=0;k<H_DIM;k+=4){
        float w0 = W_a2[(k+0)*A_DIM + c];
        float w1 = W_a2[(k+1)*A_DIM + c];
        float w2 = W_a2[(k+2)*A_DIM + c];
        float w3 = W_a2[(k+3)*A_DIM + c];
        #pragma unroll
        for(int rr=0;rr<8;rr++){
            uint2 av = *(const uint2*)&ahs[rg*8+rr][k];
            float2 p0 = bfpair(av.x), p1 = bfpair(av.y);
            acc[rr] = fmaf(p0.x,w0,fmaf(p0.y,w1,fmaf(p1.x,w2,fmaf(p1.y,w3,acc[rr]))));
        }
    }
    #pragma unroll
    for(int rr=0;rr<8;rr++){
        int grow = r0 + rg*8 + rr;
        float av = avail[(size_t)grow*A_DIM + c];
        logits[(size_t)grow*A_DIM + c] = acc[rr] + bc - (1.f-av)*1e10f;
    }

    // ---- critic: wave wid handles rows r0 + wid*16 .. +15 ----
    const int lane = tid & 63;
    const int wid  = tid >> 6;
    const u16* ch  = ac + 256;   // critic slice of the fused ac buffer
    float4 wv = *(const float4*)(W_c2 + lane*4);
    float bcv = b_c2[0];
    uint2 cv[16];
    #pragma unroll
    for(int i=0;i<16;i++){
        int row = r0 + wid*16 + i;
        cv[i] = *(const uint2*)(ch + (size_t)row*ld + lane*4);
    }
    #pragma unroll
    for(int i=0;i<16;i++){
        float2 p0 = bfpair(cv[i].x), p1 = bfpair(cv[i].y);
        float a2 = p0.x*wv.x + p0.y*wv.y + p1.x*wv.z + p1.y*wv.w;
        #pragma unroll
        for(int off=32; off>0; off>>=1) a2 += __shfl_down(a2, off, 64);
        if(lane==0) value[r0 + wid*16 + i] = a2 + bcv;
    }
}

// ---------------------------------------------------------------------------
extern "C" void kernel_launch(void* const* d_in, const int* in_sizes, int n_in,
                              void* d_out, int out_size, void* d_ws, size_t ws_size,
                              hipStream_t stream)
{
    const float* hidden = (const float*)d_in[0];
    const float* obs    = (const float*)d_in[1];
    const void*  dones  = d_in[2];
    const float* avail  = (const float*)d_in[3];
    const float* W_emb  = (const float*)d_in[4];
    const float* b_emb  = (const float*)d_in[5];
    const float* Wi     = (const float*)d_in[6];
    const float* bi     = (const float*)d_in[7];
    const float* Whr    = (const float*)d_in[8];
    const float* Whz    = (const float*)d_in[9];
    const float* Whn    = (const float*)d_in[10];
    const float* bhn    = (const float*)d_in[11];
    const float* W_a1   = (const float*)d_in[12];
    const float* b_a1   = (const float*)d_in[13];
    const float* W_a2   = (const float*)d_in[14];
    const float* b_a2   = (const float*)d_in[15];
    const float* W_c1   = (const float*)d_in[16];
    const float* b_c1   = (const float*)d_in[17];
    const float* W_c2   = (const float*)d_in[18];
    const float* b_c2   = (const float*)d_in[19];

    float* out_hidden = (float*)d_out;                       // 65536
    float* out_logits = out_hidden + (size_t)B_DIM*H_DIM;    // 4194304
    float* out_value  = out_logits + (size_t)TB*A_DIM;       // 131072

    // ---- workspace layout (chunk size adapted to ws_size, deterministic) ----
    // Operating point: Tc=256 / NC=2 (R9/R10 measured best).
    const size_t fixed = 393216 + 393216 + 262144 + 65536 + 262144 + 256 + 2048;
    int Tc = 4;
    for(int cand = 256; cand >= 4; cand >>= 1){
        size_t need = fixed + (size_t)cand*(393216 /*gi*/ + 262144 /*emb|ac*/ + 131072 /*y*/);
        if(need <= ws_size){ Tc = cand; break; }
    }
    const int NC = T_DIM / Tc;

    uint8_t* ws = (uint8_t*)d_ws;
    size_t off = 0;
    u32*  wt_b    = (u32*)(ws + off); off += 393216;   // scan weights, packed f16
    u16*  wiT     = (u16*)(ws + off); off += 393216;   // Wi^T bf16 [768][256]
    u16*  wacT    = (u16*)(ws + off); off += 262144;   // [W_a1^T | W_c1^T] bf16 [512][256]
    u16*  wembT   = (u16*)(ws + off); off += 65536;    // W_emb^T bf16 [256][128]
    float* h_carry= (float*)(ws + off); off += 262144;
    int*  flags   = (int*)(ws + off); off += 256;
    float* b_ac   = (float*)(ws + off); off += 2048;   // b_a1|b_c1 (512 f32)
    u16*  gi_c    = (u16*)(ws + off); off += (size_t)Tc*393216;
    u16*  embac_c = (u16*)(ws + off); off += (size_t)Tc*262144;  // emb [Mc][256], later ac [Mc][512]
    u16*  y_c     = (u16*)(ws + off); off += (size_t)Tc*131072;
    u16*  emb_c   = embac_c;
    u16*  ac_c    = embac_c;

    zero_flags_kernel<<<1, 64, 0, stream>>>(flags);
    detect_kernel<<<64, 256, 0, stream>>>((const unsigned char*)dones, TB, flags);
    cvt_wt_kernel<<<384, 256, 0, stream>>>(Whr, Whz, Whn, wt_b);
    cvt_wT_kernel<<<768, 256, 0, stream>>>(Wi,   wiT,  256, 768);
    cvt_wT_kernel<<<256, 256, 0, stream>>>(W_a1, wacT,          256, 256);
    cvt_wT_kernel<<<256, 256, 0, stream>>>(W_c1, wacT + 65536,  256, 256);
    cvt_wT_kernel<<<128, 256, 0, stream>>>(W_emb, wembT, 128, 256);
    concat_bias_kernel<<<1, 256, 0, stream>>>(b_a1, b_c1, b_ac);
    hipMemcpyAsync(h_carry, hidden, (size_t)B_DIM*H_DIM*sizeof(float),
                   hipMemcpyDeviceToDevice, stream);

    const int Mc = Tc*B_DIM;
    const int gy = Mc/128;

    for(int c = 0; c < NC; ++c){
        const int t0 = c*Tc;
        const float* obs_c = obs + (size_t)t0*B_DIM*OBS_DIM;
        // emb = relu(obs @ W_emb + b_emb)  (MFMA, f32 A converted in staging)
        gemm_mfma_kernel<1,1><<<dim3(2,gy), 256, 0, stream>>>(obs_c, wembT, b_emb, emb_c, Mc, 256, 128);
        // gi = emb @ Wi + bi  (MFMA)
        gemm_mfma_kernel<0,0><<<dim3(6,gy), 256, 0, stream>>>(emb_c, wiT, bi, gi_c, Mc, 768, 256);
        // GRU scan chunk: 256 blocks (one per batch row) x 1024 threads
        scan_kernel<<<256, 1024, 0, stream>>>(gi_c, dones, flags, (const u32x4*)wt_b,
                                              bhn, h_carry, y_c, t0, Tc);
        // fused actor1|critic1 head: [Mc][512] = relu(y @ [W_a1|W_c1] + b_ac)
        gemm_mfma_kernel<1,0><<<dim3(4,gy), 256, 0, stream>>>(y_c, wacT, b_ac, ac_c, Mc, 512, 256);
        // fused actor2+critic2 heads
        heads_kernel<<<Mc/64, 256, 0, stream>>>(ac_c, 512, W_a2, b_a2,
                                                avail + (size_t)t0*B_DIM*A_DIM,
                                                W_c2, b_c2,
                                                out_logits + (size_t)t0*B_DIM*A_DIM,
                                                out_value + (size_t)t0*B_DIM);
    }

    hipMemcpyAsync(out_hidden, h_carry, (size_t)B_DIM*H_DIM*sizeof(float),
                   hipMemcpyDeviceToDevice, stream);
}